// Round 2
// baseline (411.717 us; speedup 1.0000x reference)
//
#include <hip/hip_runtime.h>
#include <hip/hip_cooperative_groups.h>
#include <string.h>

namespace cg = cooperative_groups;

typedef __bf16 bf16;
typedef __bf16 bf16x4 __attribute__((ext_vector_type(4)));
typedef __bf16 bf16x8 __attribute__((ext_vector_type(8)));
typedef float f32x4 __attribute__((ext_vector_type(4)));

#define BN_EPS 1e-5f
#define NORM_EPS 1e-12f

// async global->LDS, 16B per lane. LDS dest is wave-uniform base + lane*16,
// so the lds pointer must be computed linearly in lane order (m104).
__device__ static inline __attribute__((always_inline))
void gll16(const void* gp, void* lp) {
  __builtin_amdgcn_global_load_lds(
      (const __attribute__((address_space(1))) unsigned int*)gp,
      (__attribute__((address_space(3))) unsigned int*)lp, 16, 0, 0);
}

// ================= phase bodies (shared by fused + standalone kernels) =================

// prep: Ct[k][d] = clusters[d][k] * bn_scale[k] (first 64 cols); zero asum+ssq
__device__ static inline __attribute__((always_inline))
void prep_body(int idx, const float* __restrict__ clusters,
               const float* __restrict__ bnw, const float* __restrict__ bnv,
               bf16* __restrict__ Ct, float* __restrict__ asum, float* __restrict__ ssq) {
  if (idx >= 64 * 512) return;
  if (idx < 64 * 64) { asum[idx] = 0.f; ssq[idx] = 0.f; }
  int k = idx >> 9, d = idx & 511;
  float scale = bnw[k] / sqrtf(bnv[k] + BN_EPS);
  Ct[idx] = (bf16)(clusters[d * 80 + k] * scale);
}

// assign: logits GEMM + softmax(64) + At[b][k][n] (transposed) + a_sum
// smem layout: Xl bf16[128*72] @0 (18432B) | Cl bf16[64*72] @18432 (9216B) | asum_l f32[64] @27648
__device__ static __attribute__((always_inline))
void assign_body(char* smem, int blk, int t,
                 const float* __restrict__ x, const bf16* __restrict__ Ct,
                 bf16* __restrict__ At, float* __restrict__ asum_g) {
  bf16* Xl = (bf16*)smem;
  bf16* Cl = (bf16*)(smem + 18432);
  float* asum_l = (float*)(smem + 27648);
  const int w = t >> 6;          // wave 0..3
  const int l = t & 63;
  const int q = l >> 4;          // quad 0..3
  const int m16 = l & 15;
  const int b = blk >> 3;
  const int n0 = (blk & 7) << 7; // n offset within batch
  const int row0 = blk << 7;     // global flat row

  if (t < 64) asum_l[t] = 0.f;

  f32x4 acc[2][4];
#pragma unroll
  for (int i = 0; i < 2; ++i)
#pragma unroll
    for (int j = 0; j < 4; ++j)
      acc[i][j] = (f32x4){0.f, 0.f, 0.f, 0.f};

  for (int d0 = 0; d0 < 512; d0 += 64) {
#pragma unroll
    for (int p = 0; p < 8; ++p) {           // stage X: 128 rows x 64 d fp32 -> bf16
      int id = p * 256 + t;                  // 0..2047
      int r = id >> 4, c = id & 15;          // c = 4-float chunk
      float4 v = *(const float4*)(x + (size_t)(row0 + r) * 512 + d0 + c * 4);
      bf16x4 pk;
      pk[0] = (bf16)v.x; pk[1] = (bf16)v.y; pk[2] = (bf16)v.z; pk[3] = (bf16)v.w;
      *(bf16x4*)(&Xl[r * 72 + c * 4]) = pk;
    }
#pragma unroll
    for (int p = 0; p < 2; ++p) {           // stage C tile (bf16): 64 rows x 64 d
      int id = p * 256 + t;
      int r = id >> 3, c = id & 7;
      uint4 v = *(const uint4*)(Ct + r * 512 + d0 + c * 8);
      *(uint4*)(&Cl[r * 72 + c * 8]) = v;
    }
    __syncthreads();
#pragma unroll
    for (int ks = 0; ks < 2; ++ks) {
      bf16x8 bfrag[4];
#pragma unroll
      for (int nt = 0; nt < 4; ++nt)
        bfrag[nt] = *(const bf16x8*)(&Cl[(nt * 16 + m16) * 72 + ks * 32 + q * 8]);
#pragma unroll
      for (int mt = 0; mt < 2; ++mt) {
        bf16x8 afrag = *(const bf16x8*)(&Xl[(w * 32 + mt * 16 + m16) * 72 + ks * 32 + q * 8]);
#pragma unroll
        for (int nt = 0; nt < 4; ++nt)
          acc[mt][nt] = __builtin_amdgcn_mfma_f32_16x16x32_bf16(afrag, bfrag[nt], acc[mt][nt], 0, 0, 0);
      }
    }
    __syncthreads();
  }

  // softmax over the 64 real clusters. C/D layout: row = q*4+reg, col = m16 [m89]
  bf16* Tl = Xl;  // alias, safe after last __syncthreads
  float csum[4] = {0.f, 0.f, 0.f, 0.f};
#pragma unroll
  for (int mt = 0; mt < 2; ++mt) {
#pragma unroll
    for (int r = 0; r < 4; ++r) {
      float v[4];
#pragma unroll
      for (int nt = 0; nt < 4; ++nt) v[nt] = acc[mt][nt][r];
      float mx = fmaxf(fmaxf(v[0], v[1]), fmaxf(v[2], v[3]));
#pragma unroll
      for (int off = 1; off < 16; off <<= 1) mx = fmaxf(mx, __shfl_xor(mx, off));
      float e[4];
      float s = 0.f;
#pragma unroll
      for (int nt = 0; nt < 4; ++nt) { e[nt] = __expf(v[nt] - mx); s += e[nt]; }
#pragma unroll
      for (int off = 1; off < 16; off <<= 1) s += __shfl_xor(s, off);
      float inv = 1.f / s;
      int nrow = w * 32 + mt * 16 + q * 4 + r;   // local n
#pragma unroll
      for (int nt = 0; nt < 4; ++nt) {
        bf16 ab = (bf16)(e[nt] * inv);
        Tl[(nt * 16 + m16) * 136 + nrow] = ab;   // transpose buffer [k][n]
        csum[nt] += (float)ab;
      }
    }
  }
#pragma unroll
  for (int nt = 0; nt < 4; ++nt) {
    float cs = csum[nt];
    cs += __shfl_xor(cs, 16);
    cs += __shfl_xor(cs, 32);
    if (q == 0) atomicAdd(&asum_l[nt * 16 + m16], cs);
  }
  __syncthreads();
#pragma unroll
  for (int p = 0; p < 4; ++p) {      // coalesced At store: 64 k-rows x 128 n
    int id = p * 256 + t;
    int k = id >> 4, c = id & 15;
    *(uint4*)(At + (size_t)(b * 64 + k) * 1024 + n0 + c * 8) = *(const uint4*)(&Tl[k * 136 + c * 8]);
  }
  if (t < 64) atomicAdd(&asum_g[b * 64 + t], asum_l[t]);
}

// vlad: X fp32 + At bf16 staged via async global_load_lds, 2-phase double buffer,
// both-sides XOR chunk swizzle on At (and 2-way-free chunk swizzle on X).
// smem layout: Xf f32[2][4096] @0 (32768B) | Ab bf16[2][4096] @32768 (16384B) | ssl f32[4][64] @49152
__device__ static __attribute__((always_inline))
void vlad_body(char* smem, int blk, int t,
               const float* __restrict__ x, const bf16* __restrict__ At,
               const float* __restrict__ asum_g, const float* __restrict__ c2,
               float* __restrict__ ssq_g, float* __restrict__ out) {
  float* Xf = (float*)smem;
  bf16*  Ab = (bf16*)(smem + 32768);
  float* ssl = (float*)(smem + 49152);
  const int w = t >> 6;
  const int l = t & 63;
  const int q = l >> 4;
  const int m16 = l & 15;
  const int b = blk >> 3;
  const int d0 = (blk & 7) << 6;
  const int dl = w * 16 + m16;     // this lane's d-row within the 64-chunk

  f32x4 acc[4];
#pragma unroll
  for (int j = 0; j < 4; ++j) acc[j] = (f32x4){0.f, 0.f, 0.f, 0.f};

  // stage one n-tile into buffer buf: 6 global_load_lds per thread, no VGPR round-trip.
  auto stage = [&](int buf, int nb) {
#pragma unroll
    for (int p = 0; p < 4; ++p) {      // X: 64 n x 64 d fp32 = 1024 x 16B chunks
      int chunk = p * 256 + t;          // linear LDS chunk (lane-contiguous per wave)
      int n = chunk >> 4, cp = chunk & 15;
      int c = cp ^ (((n >> 3) & 1) << 2);   // source pre-swizzle (read uses same XOR)
      const float* g = x + ((size_t)(b * 1024 + nb + n) * 512 + d0 + c * 4);
      gll16(g, &Xf[buf * 4096 + chunk * 4]);
    }
#pragma unroll
    for (int p = 0; p < 2; ++p) {      // At: 64 k x 64 n bf16 = 512 x 16B chunks
      int chunk = p * 256 + t;
      int k = chunk >> 3, cp = chunk & 7;
      int c = cp ^ (k & 7);                 // st-style row XOR, both sides
      const bf16* g = At + (size_t)(b * 64 + k) * 1024 + nb + c * 8;
      gll16(g, &Ab[buf * 4096 + chunk * 8]);
    }
  };

  stage(0, 0);
  __syncthreads();                      // drains vmcnt(0): buf0 staged

  for (int it = 0; it < 16; ++it) {
    int buf = it & 1;
    if (it < 15) stage(buf ^ 1, (it + 1) * 64);   // async prefetch next tile
#pragma unroll
    for (int ks = 0; ks < 2; ++ks) {
      bf16x8 bfrag[4];
#pragma unroll
      for (int nt = 0; nt < 4; ++nt) {
        int k = nt * 16 + m16;
        int c = (ks * 4 + q) ^ (k & 7);   // undo the staging swizzle
        bfrag[nt] = *(const bf16x8*)(&Ab[buf * 4096 + k * 64 + c * 8]);
      }
      bf16x8 af;
#pragma unroll
      for (int j = 0; j < 8; ++j) {       // Xt[d][n] column gather, fp32 -> bf16
        int n = ks * 32 + q * 8 + j;
        int dw = n * 64 + ((((dl >> 2) ^ (((n >> 3) & 1) << 2)) << 2) | (dl & 3));
        af[j] = (bf16)Xf[buf * 4096 + dw];
      }
#pragma unroll
      for (int nt = 0; nt < 4; ++nt)
        acc[nt] = __builtin_amdgcn_mfma_f32_16x16x32_bf16(af, bfrag[nt], acc[nt], 0, 0, 0);
    }
    __syncthreads();   // seals next buffer (vmcnt drain) + protects re-stage of this one
  }

  // epilogue: subtract a_sum*c2, write unscaled out, accumulate sumsq per (b,k)
  float sA[4];
#pragma unroll
  for (int nt = 0; nt < 4; ++nt) sA[nt] = asum_g[b * 64 + nt * 16 + m16];
#pragma unroll
  for (int nt = 0; nt < 4; ++nt) {
    int k = nt * 16 + m16;
    float sq = 0.f;
#pragma unroll
    for (int r = 0; r < 4; ++r) {
      int d = d0 + w * 16 + q * 4 + r;          // C/D layout: row=q*4+r, col=m16
      float v = acc[nt][r] - sA[nt] * c2[d * 64 + k];
      out[(size_t)(b * 512 + d) * 64 + k] = v;
      sq += v * v;
    }
    sq += __shfl_xor(sq, 16);                    // reduce over the 4 quads (d-rows)
    sq += __shfl_xor(sq, 32);
    if (q == 0) ssl[w * 64 + k] = sq;
  }
  __syncthreads();
  if (t < 64) {
    float s = ssl[t] + ssl[64 + t] + ssl[128 + t] + ssl[192 + t];
    atomicAdd(&ssq_g[b * 64 + t], s);
  }
}

// scale: per-(b,k) intra-norm + per-b global norm, in-place on out
// smem layout: sc f32[64] @0
__device__ static inline __attribute__((always_inline))
void scale_body(char* smem, int blk, int t,
                const float* __restrict__ ssq, float* __restrict__ out) {
  float* sc = (float*)smem;
  const int b = blk >> 3;
  const int d0 = (blk & 7) << 6;
  if (t < 64) {
    float tot = ssq[b * 64 + t];
    float rinv = 1.f / fmaxf(sqrtf(tot), NORM_EPS);
    float g = tot * rinv * rinv;     // ||v_k||^2 after intra-norm
#pragma unroll
    for (int off = 1; off < 64; off <<= 1) g += __shfl_xor(g, off);
    float ginv = 1.f / fmaxf(sqrtf(g), NORM_EPS);
    sc[t] = rinv * ginv;
  }
  __syncthreads();
  const int k = t & 63, dr = t >> 6;
  float s = sc[k];
  float* ob = out + ((size_t)b * 512 + d0) * 64;
#pragma unroll
  for (int d = dr; d < 64; d += 4) {
    int i = d * 64 + k;
    ob[i] = ob[i] * s;
  }
}

// ================= fused cooperative kernel (one dispatch, observable in top-5) =================
__global__ __launch_bounds__(256, 2) void k_fused(const float* __restrict__ x,
                                                  const float* __restrict__ clusters,
                                                  const float* __restrict__ bnw,
                                                  const float* __restrict__ bnv,
                                                  const float* __restrict__ c2,
                                                  bf16* __restrict__ Ct,
                                                  bf16* __restrict__ At,
                                                  float* __restrict__ asum,
                                                  float* __restrict__ ssq,
                                                  float* __restrict__ out) {
  __shared__ __align__(16) char smem[50176];
  cg::grid_group grid = cg::this_grid();
  prep_body(blockIdx.x * 256 + threadIdx.x, clusters, bnw, bnv, Ct, asum, ssq);
  grid.sync();
  assign_body(smem, blockIdx.x, threadIdx.x, x, Ct, At, asum);
  grid.sync();
  vlad_body(smem, blockIdx.x, threadIdx.x, x, At, asum, c2, ssq, out);
  grid.sync();
  scale_body(smem, blockIdx.x, threadIdx.x, ssq, out);
}

// ================= standalone kernels (fallback path, identical bodies) =================
__global__ __launch_bounds__(256) void k_prep(const float* __restrict__ clusters,
                                              const float* __restrict__ bnw,
                                              const float* __restrict__ bnv,
                                              bf16* __restrict__ Ct,
                                              float* __restrict__ asum,
                                              float* __restrict__ ssq) {
  prep_body(blockIdx.x * 256 + threadIdx.x, clusters, bnw, bnv, Ct, asum, ssq);
}

__global__ __launch_bounds__(256) void k_assign(const float* __restrict__ x,
                                                const bf16* __restrict__ Ct,
                                                bf16* __restrict__ At,
                                                float* __restrict__ asum_g) {
  __shared__ __align__(16) char smem[27904];
  assign_body(smem, blockIdx.x, threadIdx.x, x, Ct, At, asum_g);
}

__global__ __launch_bounds__(256, 2) void k_vlad(const float* __restrict__ x,
                                                 const bf16* __restrict__ At,
                                                 const float* __restrict__ asum_g,
                                                 const float* __restrict__ c2,
                                                 float* __restrict__ ssq_g,
                                                 float* __restrict__ out) {
  __shared__ __align__(16) char smem[50176];
  vlad_body(smem, blockIdx.x, threadIdx.x, x, At, asum_g, c2, ssq_g, out);
}

__global__ __launch_bounds__(256) void k_scale(const float* __restrict__ ssq,
                                               float* __restrict__ out) {
  __shared__ __align__(16) char smem[256];
  scale_body(smem, blockIdx.x, threadIdx.x, ssq, out);
}

extern "C" void kernel_launch(void* const* d_in, const int* in_sizes, int n_in,
                              void* d_out, int out_size, void* d_ws, size_t ws_size,
                              hipStream_t stream) {
  const float* x        = (const float*)d_in[0];
  const float* clusters = (const float*)d_in[1];
  const float* bnw      = (const float*)d_in[2];
  // d_in[3] = bn_bias, d_in[4] = bn_mean: computed-but-never-applied in the reference.
  const float* bnv      = (const float*)d_in[5];
  const float* c2       = (const float*)d_in[6];
  float* out = (float*)d_out;
  char* ws = (char*)d_ws;
  float* asum = (float*)(ws);                          // 64*64*4      = 16384 B
  float* ssq  = (float*)(ws + 16384);                  // 64*64*4      = 16384 B
  bf16*  Ct   = (bf16*)(ws + 32768);                   // 64*512*2     = 65536 B
  bf16*  At   = (bf16*)(ws + 32768 + 65536);           // 64*64*1024*2 = 8388608 B

  void* args[] = {(void*)&x, (void*)&clusters, (void*)&bnw, (void*)&bnv, (void*)&c2,
                  (void*)&Ct, (void*)&At, (void*)&asum, (void*)&ssq, (void*)&out};
  hipError_t e = hipLaunchCooperativeKernel((const void*)k_fused, dim3(512), dim3(256),
                                            args, 0, stream);
  if (e != hipSuccess) {
    // fallback: identical 4-kernel pipeline
    k_prep<<<128, 256, 0, stream>>>(clusters, bnw, bnv, Ct, asum, ssq);
    k_assign<<<512, 256, 0, stream>>>(x, Ct, At, asum);
    k_vlad<<<512, 256, 0, stream>>>(x, At, asum, c2, ssq, out);
    k_scale<<<512, 256, 0, stream>>>(ssq, out);
  }
}

// Round 3
// 297.960 us; speedup vs baseline: 1.3818x; 1.3818x over previous
//
#include <hip/hip_runtime.h>
#include <string.h>

typedef __bf16 bf16;
typedef __bf16 bf16x4 __attribute__((ext_vector_type(4)));
typedef __bf16 bf16x8 __attribute__((ext_vector_type(8)));
typedef float f32x4 __attribute__((ext_vector_type(4)));

#define BN_EPS 1e-5f
#define NORM_EPS 1e-12f

// async global->LDS, 16B per lane. LDS dest is wave-uniform base + lane*16,
// so the lds pointer must be computed linearly in lane order (m104).
__device__ static inline __attribute__((always_inline))
void gll16(const void* gp, void* lp) {
  __builtin_amdgcn_global_load_lds(
      (const __attribute__((address_space(1))) unsigned int*)gp,
      (__attribute__((address_space(3))) unsigned int*)lp, 16, 0, 0);
}

// ---- prep: Ct[k][d] = clusters[d][k] * bn_scale[k]; zero asum + cnt ----
__global__ __launch_bounds__(256) void k_prep(const float* __restrict__ clusters,
                                              const float* __restrict__ bnw,
                                              const float* __restrict__ bnv,
                                              bf16* __restrict__ Ct,
                                              float* __restrict__ asum,
                                              unsigned* __restrict__ cnt) {
  int idx = blockIdx.x * 256 + threadIdx.x;   // 0..32767 (= 64*512)
  if (idx < 64 * 64) asum[idx] = 0.f;
  if (idx < 64) cnt[idx] = 0u;
  int k = idx >> 9, d = idx & 511;
  float scale = bnw[k] / sqrtf(bnv[k] + BN_EPS);
  Ct[idx] = (bf16)(clusters[d * 80 + k] * scale);
}

// ---- assign: logits GEMM + softmax(64) + At[b][k][n] (transposed) + a_sum ----
// Round-3 change: 1024 blocks x 64 rows (was 512 x 128) -> 4 blocks/CU for
// latency hiding in the stage->sync->MFMA->sync chain. GEMM math identical.
__global__ __launch_bounds__(256) void k_assign(const float* __restrict__ x,
                                                const bf16* __restrict__ Ct,
                                                bf16* __restrict__ At,
                                                float* __restrict__ asum_g) {
  __shared__ __align__(16) bf16 Xl[64 * 72];    // 64 rows x 64 d, pitch 72 (9216B)
  __shared__ __align__(16) bf16 Cl[64 * 72];    // 64 clusters x 64 d, pitch 72
  __shared__ float asum_l[64];
  const int t = threadIdx.x;
  const int w = t >> 6;          // wave 0..3
  const int l = t & 63;
  const int q = l >> 4;          // quad 0..3
  const int m16 = l & 15;
  const int blk = blockIdx.x;    // 0..1023
  const int b = blk >> 4;
  const int n0 = (blk & 15) << 6; // n offset within batch
  const int row0 = blk << 6;      // global flat row

  if (t < 64) asum_l[t] = 0.f;

  f32x4 acc[4];
#pragma unroll
  for (int j = 0; j < 4; ++j) acc[j] = (f32x4){0.f, 0.f, 0.f, 0.f};

  for (int d0 = 0; d0 < 512; d0 += 64) {
#pragma unroll
    for (int p = 0; p < 4; ++p) {           // stage X: 64 rows x 64 d fp32 -> bf16
      int id = p * 256 + t;                  // 0..1023
      int r = id >> 4, c = id & 15;          // c = 4-float chunk
      float4 v = *(const float4*)(x + (size_t)(row0 + r) * 512 + d0 + c * 4);
      bf16x4 pk;
      pk[0] = (bf16)v.x; pk[1] = (bf16)v.y; pk[2] = (bf16)v.z; pk[3] = (bf16)v.w;
      *(bf16x4*)(&Xl[r * 72 + c * 4]) = pk;
    }
#pragma unroll
    for (int p = 0; p < 2; ++p) {           // stage C tile (bf16): 64 rows x 64 d
      int id = p * 256 + t;
      int r = id >> 3, c = id & 7;
      uint4 v = *(const uint4*)(Ct + r * 512 + d0 + c * 8);
      *(uint4*)(&Cl[r * 72 + c * 8]) = v;
    }
    __syncthreads();
#pragma unroll
    for (int ks = 0; ks < 2; ++ks) {
      bf16x8 bfrag[4];
#pragma unroll
      for (int nt = 0; nt < 4; ++nt)
        bfrag[nt] = *(const bf16x8*)(&Cl[(nt * 16 + m16) * 72 + ks * 32 + q * 8]);
      bf16x8 afrag = *(const bf16x8*)(&Xl[(w * 16 + m16) * 72 + ks * 32 + q * 8]);
#pragma unroll
      for (int nt = 0; nt < 4; ++nt)
        acc[nt] = __builtin_amdgcn_mfma_f32_16x16x32_bf16(afrag, bfrag[nt], acc[nt], 0, 0, 0);
    }
    __syncthreads();
  }

  // softmax over the 64 real clusters. C/D layout: row = q*4+reg, col = m16 [m89]
  bf16* Tl = Xl;  // alias, safe after last __syncthreads; [k][n] pitch 72, 64 n
  float csum[4] = {0.f, 0.f, 0.f, 0.f};
#pragma unroll
  for (int r = 0; r < 4; ++r) {
    float v[4];
#pragma unroll
    for (int nt = 0; nt < 4; ++nt) v[nt] = acc[nt][r];
    float mx = fmaxf(fmaxf(v[0], v[1]), fmaxf(v[2], v[3]));
#pragma unroll
    for (int off = 1; off < 16; off <<= 1) mx = fmaxf(mx, __shfl_xor(mx, off));
    float e[4];
    float s = 0.f;
#pragma unroll
    for (int nt = 0; nt < 4; ++nt) { e[nt] = __expf(v[nt] - mx); s += e[nt]; }
#pragma unroll
    for (int off = 1; off < 16; off <<= 1) s += __shfl_xor(s, off);
    float inv = 1.f / s;
    int nrow = w * 16 + q * 4 + r;   // local n (0..63)
#pragma unroll
    for (int nt = 0; nt < 4; ++nt) {
      bf16 ab = (bf16)(e[nt] * inv);
      Tl[(nt * 16 + m16) * 72 + nrow] = ab;   // transpose buffer [k][n]
      csum[nt] += (float)ab;
    }
  }
#pragma unroll
  for (int nt = 0; nt < 4; ++nt) {
    float cs = csum[nt];
    cs += __shfl_xor(cs, 16);
    cs += __shfl_xor(cs, 32);
    if (q == 0) atomicAdd(&asum_l[nt * 16 + m16], cs);
  }
  __syncthreads();
#pragma unroll
  for (int p = 0; p < 2; ++p) {      // coalesced At store: 64 k-rows x 64 n
    int id = p * 256 + t;
    int k = id >> 3, c = id & 7;
    *(uint4*)(At + (size_t)(b * 64 + k) * 1024 + n0 + c * 8) = *(const uint4*)(&Tl[k * 72 + c * 8]);
  }
  if (t < 64) atomicAdd(&asum_g[b * 64 + t], asum_l[t]);
}

// ---- vlad: 512 blocks = (b, 64-wide d-chunk). gll16 staging + double buffer
//      (round-1 structure, verified). Round-3 change: k_scale is MERGED here via
//      the last-block-per-batch pattern: each block writes its ssq partial
//      (race-free), fence + agent-scope counter; the 8th arriver for batch b
//      computes both norms and rescales b's out slice in place. ----
__global__ __launch_bounds__(256, 2) void k_vlad(const float* __restrict__ x,
                                                 const bf16* __restrict__ At,
                                                 const float* __restrict__ asum_g,
                                                 const float* __restrict__ c2,
                                                 float* __restrict__ ssq_p,
                                                 unsigned* __restrict__ cnt,
                                                 float* __restrict__ out) {
  __shared__ __align__(16) float Xf[2][64 * 64];  // 64 n x 64 d fp32, chunk-swizzled
  __shared__ __align__(16) bf16 Ab[2][64 * 64];   // 64 k x 64 n bf16, chunk-swizzled
  __shared__ float ssl[4][64];
  __shared__ unsigned lastf;
  const int t = threadIdx.x;
  const int w = t >> 6;
  const int l = t & 63;
  const int q = l >> 4;
  const int m16 = l & 15;
  const int blk = blockIdx.x;
  const int b = blk >> 3;
  const int d0 = (blk & 7) << 6;
  const int dl = w * 16 + m16;     // this lane's d-row within the 64-chunk

  f32x4 acc[4];
#pragma unroll
  for (int j = 0; j < 4; ++j) acc[j] = (f32x4){0.f, 0.f, 0.f, 0.f};

  auto stage = [&](int buf, int nb) {
#pragma unroll
    for (int p = 0; p < 4; ++p) {      // X: 64 n x 64 d fp32 = 1024 x 16B chunks
      int chunk = p * 256 + t;
      int n = chunk >> 4, cp = chunk & 15;
      int c = cp ^ (((n >> 3) & 1) << 2);   // source pre-swizzle (read uses same XOR)
      const float* g = x + ((size_t)(b * 1024 + nb + n) * 512 + d0 + c * 4);
      gll16(g, &Xf[buf][chunk * 4]);
    }
#pragma unroll
    for (int p = 0; p < 2; ++p) {      // At: 64 k x 64 n bf16 = 512 x 16B chunks
      int chunk = p * 256 + t;
      int k = chunk >> 3, cp = chunk & 7;
      int c = cp ^ (k & 7);                 // st-style row XOR, both sides
      const bf16* g = At + (size_t)(b * 64 + k) * 1024 + nb + c * 8;
      gll16(g, &Ab[buf][chunk * 8]);
    }
  };

  stage(0, 0);
  __syncthreads();                      // drains vmcnt(0): buf0 staged

  for (int it = 0; it < 16; ++it) {
    int buf = it & 1;
    if (it < 15) stage(buf ^ 1, (it + 1) * 64);   // async prefetch next tile
#pragma unroll
    for (int ks = 0; ks < 2; ++ks) {
      bf16x8 bfrag[4];
#pragma unroll
      for (int nt = 0; nt < 4; ++nt) {
        int k = nt * 16 + m16;
        int c = (ks * 4 + q) ^ (k & 7);   // undo the staging swizzle
        bfrag[nt] = *(const bf16x8*)(&Ab[buf][k * 64 + c * 8]);
      }
      bf16x8 af;
#pragma unroll
      for (int j = 0; j < 8; ++j) {       // Xt[d][n] column gather, fp32 -> bf16
        int n = ks * 32 + q * 8 + j;
        int dw = n * 64 + ((((dl >> 2) ^ (((n >> 3) & 1) << 2)) << 2) | (dl & 3));
        af[j] = (bf16)Xf[buf][dw];
      }
#pragma unroll
      for (int nt = 0; nt < 4; ++nt)
        acc[nt] = __builtin_amdgcn_mfma_f32_16x16x32_bf16(af, bfrag[nt], acc[nt], 0, 0, 0);
    }
    __syncthreads();
  }

  // epilogue: subtract a_sum*c2, write unscaled out, per-(b,k) sumsq partial
  float sA[4];
#pragma unroll
  for (int nt = 0; nt < 4; ++nt) sA[nt] = asum_g[b * 64 + nt * 16 + m16];
#pragma unroll
  for (int nt = 0; nt < 4; ++nt) {
    int k = nt * 16 + m16;
    float sq = 0.f;
#pragma unroll
    for (int r = 0; r < 4; ++r) {
      int d = d0 + w * 16 + q * 4 + r;          // C/D layout: row=q*4+r, col=m16
      float v = acc[nt][r] - sA[nt] * c2[d * 64 + k];
      out[(size_t)(b * 512 + d) * 64 + k] = v;
      sq += v * v;
    }
    sq += __shfl_xor(sq, 16);                    // reduce over the 4 quads (d-rows)
    sq += __shfl_xor(sq, 32);
    if (q == 0) ssl[w][k] = sq;
  }
  __syncthreads();
  if (t < 64) {
    float s = ssl[0][t] + ssl[1][t] + ssl[2][t] + ssl[3][t];
    ssq_p[(size_t)blk * 64 + t] = s;             // race-free partial (no atomics)
  }
  __syncthreads();   // all out + ssq_p stores retired (vmcnt 0) before the fence

  if (t == 0) {
    __threadfence();                             // agent release: writeback our L2
    lastf = __hip_atomic_fetch_add(&cnt[b], 1u, __ATOMIC_ACQ_REL,
                                   __HIP_MEMORY_SCOPE_AGENT);
  }
  __syncthreads();
  if (lastf == 7) {                              // we are the 8th block for batch b
    __threadfence();                             // agent acquire: invalidate stale lines
    float* scl = &ssl[0][0];                     // reuse LDS for the 64 scale factors
    if (t < 64) {
      float tot = 0.f;
#pragma unroll
      for (int j = 0; j < 8; ++j) tot += ssq_p[(size_t)(b * 8 + j) * 64 + t];
      float rinv = 1.f / fmaxf(sqrtf(tot), NORM_EPS);
      float g = tot * rinv * rinv;               // ||v_k||^2 after intra-norm
#pragma unroll
      for (int off = 1; off < 64; off <<= 1) g += __shfl_xor(g, off);
      float ginv = 1.f / fmaxf(sqrtf(g), NORM_EPS);
      scl[t] = rinv * ginv;
    }
    __syncthreads();
    const int k = t & 63, dr = t >> 6;
    float s = scl[k];
    float* ob = out + (size_t)b * 512 * 64;
    for (int d = dr; d < 512; d += 4) {
      size_t i = (size_t)d * 64 + k;
      ob[i] = ob[i] * s;
    }
  }
}

extern "C" void kernel_launch(void* const* d_in, const int* in_sizes, int n_in,
                              void* d_out, int out_size, void* d_ws, size_t ws_size,
                              hipStream_t stream) {
  const float* x        = (const float*)d_in[0];
  const float* clusters = (const float*)d_in[1];
  const float* bnw      = (const float*)d_in[2];
  // d_in[3] = bn_bias, d_in[4] = bn_mean: computed-but-never-applied in the reference.
  const float* bnv      = (const float*)d_in[5];
  const float* c2       = (const float*)d_in[6];
  float* out = (float*)d_out;
  char* ws = (char*)d_ws;
  float*    asum  = (float*)(ws);                      // 64*64*4      = 16384 B
  unsigned* cnt   = (unsigned*)(ws + 16384);           // 64*4         = 256 B
  float*    ssq_p = (float*)(ws + 32768);              // 512*64*4     = 131072 B
  bf16*     Ct    = (bf16*)(ws + 32768 + 131072);      // 64*512*2     = 65536 B
  bf16*     At    = (bf16*)(ws + 32768 + 131072 + 65536);  // 64*64*1024*2 = 8388608 B

  k_prep<<<128, 256, 0, stream>>>(clusters, bnw, bnv, Ct, asum, cnt);
  k_assign<<<1024, 256, 0, stream>>>(x, Ct, At, asum);
  k_vlad<<<512, 256, 0, stream>>>(x, At, asum, c2, ssq_p, cnt, out);
}

// Round 4
// 233.087 us; speedup vs baseline: 1.7664x; 1.2783x over previous
//
#include <hip/hip_runtime.h>
#include <string.h>

typedef __bf16 bf16;
typedef __bf16 bf16x4 __attribute__((ext_vector_type(4)));
typedef __bf16 bf16x8 __attribute__((ext_vector_type(8)));
typedef float f32x4 __attribute__((ext_vector_type(4)));

#define BN_EPS 1e-5f
#define NORM_EPS 1e-12f

// ---- prep: Ct[k][d] = clusters[d][k] * bn_scale[k]; zero asum ----
__global__ __launch_bounds__(256) void k_prep(const float* __restrict__ clusters,
                                              const float* __restrict__ bnw,
                                              const float* __restrict__ bnv,
                                              bf16* __restrict__ Ct,
                                              float* __restrict__ asum) {
  int idx = blockIdx.x * 256 + threadIdx.x;   // 0..32767 (= 64*512)
  if (idx < 64 * 64) asum[idx] = 0.f;
  int k = idx >> 9, d = idx & 511;
  float scale = bnw[k] / sqrtf(bnv[k] + BN_EPS);
  Ct[idx] = (bf16)(clusters[d * 80 + k] * scale);
}

// ---- fused: one pass over x. 256 blocks = (b, n-quarter). Per 64-n chunk:
//   logits GEMM (Ct resident, verified assign tile layout) -> softmax ->
//   a in LDS [k][n] pitch 72 (verified) -> V-GEMM accumulate in registers.
//   Block writes V partial (512x64 fp32) + atomicAdd a_sum partial.
//   X LDS layout: subtiled X2[dc=d/16][ng=n/4][nr^=(ng&3)][dl=d%16] bf16 —
//   serves logits A-frag (contiguous bf16x8 along d) AND V-GEMM transposed
//   gather (u16, 2-way max conflict) from ONE 64 KB buffer. ----
__global__ __launch_bounds__(256) void k_fused(const float* __restrict__ x,
                                               const bf16* __restrict__ Ct,
                                               float* __restrict__ Vp,
                                               float* __restrict__ asum_g) {
  __shared__ __align__(16) bf16 X2[32768];      // 64 KB
  __shared__ __align__(16) bf16 Cl[8][64 * 72]; // 72 KB (8 verified assign tiles)
  __shared__ __align__(16) bf16 Tl[64 * 72];    // 9 KB  a-tile [k][n]
  __shared__ float asum_l[64];
  const int t = threadIdx.x;
  const int w = t >> 6;          // wave 0..3
  const int l = t & 63;
  const int q = l >> 4;          // quad 0..3
  const int m16 = l & 15;
  const int b = blockIdx.x >> 2;       // batch
  const int q4 = blockIdx.x & 3;       // n-quarter
  const int nbase = q4 << 8;           // n offset within batch

  // load Ct resident: 8 tiles of [64k][64d] pitch 72 (same as verified assign stage)
#pragma unroll
  for (int p = 0; p < 16; ++p) {
    int id = p * 256 + t;              // 0..4095
    int tile = id >> 9, r = (id >> 3) & 63, c = id & 7;
    *(uint4*)(&Cl[tile][r * 72 + c * 8]) = *(const uint4*)(Ct + r * 512 + tile * 64 + c * 8);
  }
  if (t < 64) asum_l[t] = 0.f;

  f32x4 vacc[8][4];
#pragma unroll
  for (int i = 0; i < 8; ++i)
#pragma unroll
    for (int j = 0; j < 4; ++j) vacc[i][j] = (f32x4){0.f, 0.f, 0.f, 0.f};

  const int angL = w * 4 + (m16 >> 2);          // logits-row ng
  const int anrL = (m16 & 3) ^ (angL & 3);      // swizzled nr

  for (int ch = 0; ch < 4; ++ch) {
    const int n0 = nbase + ch * 64;
    // ---- stage X chunk: 64 n x 512 d fp32 -> bf16, subtiled+swizzled ----
#pragma unroll 8
    for (int p = 0; p < 32; ++p) {
      int id = p * 256 + t;            // 0..8191
      int nn = id >> 7, c = id & 127;  // c = 4-float chunk of d
      float4 v = *(const float4*)(x + (size_t)(b * 1024 + n0 + nn) * 512 + c * 4);
      int dc = c >> 2, dl0 = (c & 3) * 4;
      int ng = nn >> 2, nrp = (nn & 3) ^ (ng & 3);
      bf16x4 pk;
      pk[0] = (bf16)v.x; pk[1] = (bf16)v.y; pk[2] = (bf16)v.z; pk[3] = (bf16)v.w;
      *(bf16x4*)(&X2[dc * 1024 + ng * 64 + nrp * 16 + dl0]) = pk;
    }
    __syncthreads();   // X2 staged (first iter: also seals Cl)

    // ---- logits GEMM: lacc[nt] over K=512 (verified assign structure) ----
    f32x4 lacc[4];
#pragma unroll
    for (int j = 0; j < 4; ++j) lacc[j] = (f32x4){0.f, 0.f, 0.f, 0.f};
#pragma unroll
    for (int dt8 = 0; dt8 < 8; ++dt8) {
#pragma unroll
      for (int ks = 0; ks < 2; ++ks) {
        int dc = dt8 * 4 + ks * 2 + (q >> 1);
        bf16x8 afrag = *(const bf16x8*)(&X2[dc * 1024 + angL * 64 + anrL * 16 + (q & 1) * 8]);
#pragma unroll
        for (int nt = 0; nt < 4; ++nt) {
          bf16x8 bfrag = *(const bf16x8*)(&Cl[dt8][(nt * 16 + m16) * 72 + ks * 32 + q * 8]);
          lacc[nt] = __builtin_amdgcn_mfma_f32_16x16x32_bf16(afrag, bfrag, lacc[nt], 0, 0, 0);
        }
      }
    }

    // ---- softmax over 64 k (verified). C/D: row n = w*16+q*4+r, col k = nt*16+m16 ----
    float csum[4] = {0.f, 0.f, 0.f, 0.f};
#pragma unroll
    for (int r = 0; r < 4; ++r) {
      float v[4];
#pragma unroll
      for (int nt = 0; nt < 4; ++nt) v[nt] = lacc[nt][r];
      float mx = fmaxf(fmaxf(v[0], v[1]), fmaxf(v[2], v[3]));
#pragma unroll
      for (int off = 1; off < 16; off <<= 1) mx = fmaxf(mx, __shfl_xor(mx, off));
      float e[4];
      float s = 0.f;
#pragma unroll
      for (int nt = 0; nt < 4; ++nt) { e[nt] = __expf(v[nt] - mx); s += e[nt]; }
#pragma unroll
      for (int off = 1; off < 16; off <<= 1) s += __shfl_xor(s, off);
      float inv = 1.f / s;
      int nrow = w * 16 + q * 4 + r;   // local n (0..63)
#pragma unroll
      for (int nt = 0; nt < 4; ++nt) {
        bf16 ab = (bf16)(e[nt] * inv);
        Tl[(nt * 16 + m16) * 72 + nrow] = ab;
        csum[nt] += (float)ab;
      }
    }
#pragma unroll
    for (int nt = 0; nt < 4; ++nt) {
      float cs = csum[nt];
      cs += __shfl_xor(cs, 16);
      cs += __shfl_xor(cs, 32);
      if (q == 0) atomicAdd(&asum_l[nt * 16 + m16], cs);
    }
    __syncthreads();   // Tl ready for all waves

    // ---- V-GEMM: vacc[dt][nt] += Xt[d][n] * a[n][k]; wave w owns d in [w*128, w*128+128) ----
#pragma unroll
    for (int ks = 0; ks < 2; ++ks) {
      bf16x8 bfr[4];
#pragma unroll
      for (int nt = 0; nt < 4; ++nt)
        bfr[nt] = *(const bf16x8*)(&Tl[(nt * 16 + m16) * 72 + ks * 32 + q * 8]);
#pragma unroll
      for (int dt = 0; dt < 8; ++dt) {
        int dc = w * 8 + dt;
        bf16x8 af;
#pragma unroll
        for (int j = 0; j < 8; ++j) {
          int ng = ks * 8 + q * 2 + (j >> 2);
          int nrp = (j & 3) ^ (ng & 3);
          af[j] = X2[dc * 1024 + ng * 64 + nrp * 16 + m16];
        }
#pragma unroll
        for (int nt = 0; nt < 4; ++nt)
          vacc[dt][nt] = __builtin_amdgcn_mfma_f32_16x16x32_bf16(af, bfr[nt], vacc[dt][nt], 0, 0, 0);
      }
    }
    __syncthreads();   // before next chunk overwrites X2/Tl
  }

  if (t < 64) atomicAdd(&asum_g[b * 64 + t], asum_l[t]);

  // write V partial: Vp[q4][b][d][k]. C/D: row d = (w*8+dt)*16 + q*4 + r, col k = nt*16+m16
  float* vp = Vp + (size_t)(q4 * 64 + b) * 512 * 64;
#pragma unroll
  for (int dt = 0; dt < 8; ++dt) {
#pragma unroll
    for (int nt = 0; nt < 4; ++nt) {
      int k = nt * 16 + m16;
#pragma unroll
      for (int r = 0; r < 4; ++r) {
        int d = (w * 8 + dt) * 16 + q * 4 + r;
        vp[(size_t)d * 64 + k] = vacc[dt][nt][r];
      }
    }
  }
}

// ---- combine: out = sum of 4 partials - a_sum*c2; write unscaled out + ssq partials ----
__global__ __launch_bounds__(256) void k_combine(const float* __restrict__ Vp,
                                                 const float* __restrict__ asum_g,
                                                 const float* __restrict__ c2,
                                                 float* __restrict__ ssq_p,
                                                 float* __restrict__ out) {
  __shared__ float ssl[4][64];
  const int t = threadIdx.x;
  const int b = blockIdx.x >> 3;
  const int d0 = (blockIdx.x & 7) << 6;
  const int k = t & 63, tg = t >> 6;
  const size_t QS = (size_t)64 * 512 * 64;
  float sA = asum_g[b * 64 + k];
  float sq = 0.f;
#pragma unroll
  for (int p = 0; p < 16; ++p) {
    int d = d0 + p * 4 + tg;
    size_t off = ((size_t)b * 512 + d) * 64 + k;
    float v = Vp[off] + Vp[QS + off] + Vp[2 * QS + off] + Vp[3 * QS + off]
              - sA * c2[d * 64 + k];
    out[off] = v;
    sq += v * v;
  }
  ssl[tg][k] = sq;
  __syncthreads();
  if (t < 64) ssq_p[(size_t)blockIdx.x * 64 + t] = ssl[0][t] + ssl[1][t] + ssl[2][t] + ssl[3][t];
}

// ---- scale: per-(b,k) intra-norm + per-b global norm, in-place on out (verified) ----
__global__ __launch_bounds__(256) void k_scale(const float* __restrict__ ssq_p,
                                               float* __restrict__ out) {
  __shared__ float sc[64];
  const int t = threadIdx.x;
  const int b = blockIdx.x >> 3;
  const int d0 = (blockIdx.x & 7) << 6;
  if (t < 64) {
    float tot = 0.f;
#pragma unroll
    for (int j = 0; j < 8; ++j) tot += ssq_p[(size_t)(b * 8 + j) * 64 + t];
    float rinv = 1.f / fmaxf(sqrtf(tot), NORM_EPS);
    float g = tot * rinv * rinv;     // ||v_k||^2 after intra-norm
#pragma unroll
    for (int off = 1; off < 64; off <<= 1) g += __shfl_xor(g, off);
    float ginv = 1.f / fmaxf(sqrtf(g), NORM_EPS);
    sc[t] = rinv * ginv;
  }
  __syncthreads();
  const int k = t & 63, dr = t >> 6;
  float s = sc[k];
  float* ob = out + ((size_t)b * 512 + d0) * 64;
#pragma unroll
  for (int d = dr; d < 64; d += 4) {
    int i = d * 64 + k;
    ob[i] = ob[i] * s;
  }
}

extern "C" void kernel_launch(void* const* d_in, const int* in_sizes, int n_in,
                              void* d_out, int out_size, void* d_ws, size_t ws_size,
                              hipStream_t stream) {
  const float* x        = (const float*)d_in[0];
  const float* clusters = (const float*)d_in[1];
  const float* bnw      = (const float*)d_in[2];
  // d_in[3] = bn_bias, d_in[4] = bn_mean: computed-but-never-applied in the reference.
  const float* bnv      = (const float*)d_in[5];
  const float* c2       = (const float*)d_in[6];
  float* out = (float*)d_out;
  char* ws = (char*)d_ws;
  float* asum  = (float*)(ws);                         // 64*64*4        = 16384 B
  float* ssq_p = (float*)(ws + 32768);                 // 512*64*4       = 131072 B
  bf16*  Ct    = (bf16*)(ws + 32768 + 131072);         // 64*512*2       = 65536 B
  float* Vp    = (float*)(ws + 32768 + 131072 + 65536);// 4*64*512*64*4  = 33554432 B

  k_prep<<<128, 256, 0, stream>>>(clusters, bnw, bnv, Ct, asum);
  k_fused<<<256, 256, 0, stream>>>(x, Ct, Vp, asum);
  k_combine<<<512, 256, 0, stream>>>(Vp, asum, c2, ssq_p, out);
  k_scale<<<512, 256, 0, stream>>>(ssq_p, out);
}